// Round 10
// baseline (208.428 us; speedup 1.0000x reference)
//
#include <hip/hip_runtime.h>
#include <math.h>
#include <stdint.h>

typedef _Float16 half8 __attribute__((ext_vector_type(8)));
typedef float floatx4 __attribute__((ext_vector_type(4)));

#define NTOK 16384
#define DIM  2048
#define NEXP 64
#define TPB  32                    // tokens per block
#define NBLK (NTOK / TPB)          // 512 blocks -> 2 per CU (the occupancy probe)
#define KSPL 8                     // K-split: one slice per wave
#define KW   (DIM / KSPL)          // 256 k per wave
#define KC   32                    // k per chunk
#define NCH  (KW / KC)             // 8 chunks
#define WSW_H8 16384               // half8 slots per split
#define WSW_BYTES (2 * WSW_H8 * 16)

#define SLOT_B  4096               // A slot: 32 rows x 128 B (one 32-k chunk)
#define WAVE_B  (2 * SLOT_B)       // ring-2, wave-private
#define ARING_B (8 * WAVE_B)       // 64 KB; aliased by 8 reduction slabs (8 x 8 KB)
#define FIN_F   (TPB * 65)         // final logits, stride-65

// ---- prep: split W (fp32) into f16 hi + scaled-lo (2^11), B-fragment order:
// slot(sg,tg,lane) = (sg*4+tg)*64+lane holds W[tg*16+(lane&15)][sg*32+(lane>>4)*8 + 0..7]
__global__ void wprep_kernel(const float* __restrict__ W, _Float16* __restrict__ wsw) {
    const int id   = blockIdx.x * blockDim.x + threadIdx.x; // 0..16383
    const int lane = id & 63;
    const int tg   = (id >> 6) & 3;
    const int sg   = id >> 8;                               // 0..63
    const int e    = tg * 16 + (lane & 15);
    const int k    = sg * 32 + (lane >> 4) * 8;
    const float* src = W + (size_t)e * DIM + k;
    half8 h, l;
#pragma unroll
    for (int j = 0; j < 8; j++) {
        const float v  = src[j];
        const _Float16 hh = (_Float16)v;
        h[j] = hh;
        l[j] = (_Float16)((v - (float)hh) * 2048.0f);
    }
    const size_t slot = (size_t)(sg * 4 + tg) * 64 + lane;
    ((half8*)wsw)[slot]          = h;
    ((half8*)wsw)[WSW_H8 + slot] = l;
}

__device__ __forceinline__ void split_a(const float4& v0, const float4& v1,
                                        half8& hi, half8& lo) {
    const float av[8] = {v0.x, v0.y, v0.z, v0.w, v1.x, v1.y, v1.z, v1.w};
#pragma unroll
    for (int j = 0; j < 8; j++) {
        const _Float16 hh = (_Float16)av[j];
        hi[j] = hh;
        lo[j] = (_Float16)((av[j] - (float)hh) * 2048.0f);
    }
}

// async global->LDS DMA, 16 B/lane. LDS dest = WAVE-UNIFORM base (HW appends lane*16).
__device__ __forceinline__ void dma16(const void* g, const char* l) {
    __builtin_amdgcn_global_load_lds(
        (const __attribute__((address_space(1))) unsigned int*)(uintptr_t)g,
        (__attribute__((address_space(3))) unsigned int*)(uintptr_t)l,
        16, 0, 0);
}

template <int N>
__device__ __forceinline__ void wait_vm() {
    asm volatile("s_waitcnt vmcnt(%0)" :: "n"(N) : "memory");
}

// Occupancy probe: R8's barrier-free K-split, halved per-wave footprint so TWO
// blocks co-reside per CU (16 waves/CU = 4/SIMD, 2x R8). Wave ks owns
// 32 tok x 64 exp x 256 k. Per iter c (order sealed by fences; B issued BEFORE
// A-dma so in-order vmcnt retirement never forces an A drain):
//   [B(c) 8 loads][A(c+1) 4 dma][wait vmcnt(12): A(c) landed]
//   [ds_read + 24 MFMA; compiler waits B(c) at vmcnt(4)]
template <bool USE_WS>
__global__ __launch_bounds__(512, 4)
void gating_kernel(const float* __restrict__ x, const float* __restrict__ W,
                   const _Float16* __restrict__ wsw, const float* __restrict__ bias,
                   float* __restrict__ out)
{
    __shared__ char  aring[ARING_B];   // 64 KB: k-loop A ring; epilogue: 8 slabs
    __shared__ float fin[FIN_F];
    __shared__ float bsh[NEXP];

    const int tid  = threadIdx.x;
    const int lane = tid & 63;
    const int ks   = tid >> 6;          // 0..7: K-slice (wave id)
    const int col  = lane & 15;
    const int quad = lane >> 4;
    const int tok0 = blockIdx.x * TPB;

    if (tid < NEXP) bsh[tid] = bias[tid];

    // A dma: op i covers rows 8i..8i+7 (128 B per row-chunk). XOR piece swizzle:
    // LDS piece pz = lane&7 holds global piece pz ^ (row&7); row&7 == lane>>3.
    const int arow = lane >> 3;
    const int agp  = (lane & 7) ^ arow;
    const float* gA = x + (size_t)(tok0 + arow) * DIM + ks * KW + agp * 4;
    char* const wbase = aring + ks * WAVE_B;  // wave-private ring-2

    floatx4 accm[2][4], accl[2][4];
#pragma unroll
    for (int m = 0; m < 2; m++)
#pragma unroll
        for (int t = 0; t < 4; t++) { accm[m][t] = (floatx4){0,0,0,0}; accl[m][t] = (floatx4){0,0,0,0}; }

    // prologue: chunk 0 -> slot 0 (4 dma ops, rows 8i..8i+7 each)
#pragma unroll
    for (int i = 0; i < 4; i++)
        dma16(gA + (size_t)i * 8 * DIM, wbase + i * 1024);

#pragma unroll
    for (int c = 0; c < NCH; ++c) {
        const int sg = ks * NCH + c;          // global k-step 0..63
        half8  bh[4], bl[4];
        float4 bf0[4], bf1[4];
        if constexpr (USE_WS) {
#pragma unroll
            for (int t = 0; t < 4; t++) {
                bh[t] = ((const half8*)wsw)[(size_t)(sg * 4 + t) * 64 + lane];
                bl[t] = ((const half8*)wsw)[WSW_H8 + (size_t)(sg * 4 + t) * 64 + lane];
            }
        } else {
#pragma unroll
            for (int t = 0; t < 4; t++) {
                const float* wr = W + (size_t)(t * 16 + col) * DIM + sg * 32 + quad * 8;
                bf0[t] = *(const float4*)wr;
                bf1[t] = *(const float4*)(wr + 4);
            }
        }
        asm volatile("" ::: "memory");
        if (c + 1 < NCH) {
#pragma unroll
            for (int i = 0; i < 4; i++)
                dma16(gA + (size_t)i * 8 * DIM + (c + 1) * KC,
                      wbase + ((c + 1) & 1) * SLOT_B + i * 1024);
        }
        asm volatile("" ::: "memory");
        if (c + 1 < NCH) wait_vm<12>();   // newer = B(c)8 + A(c+1)4; A(c) landed
        else             wait_vm<8>();    // newer = B(c)8 only
        asm volatile("" ::: "memory");

        const char* Ab = wbase + (c & 1) * SLOT_B;
#pragma unroll
        for (int m = 0; m < 2; m++) {
            const int row = m * 16 + col;
            const float4 v0 = *(const float4*)(Ab + row * 128 + (((2 * quad + 0) ^ (row & 7))) * 16);
            const float4 v1 = *(const float4*)(Ab + row * 128 + (((2 * quad + 1) ^ (row & 7))) * 16);
            half8 ah, al;
            split_a(v0, v1, ah, al);
#pragma unroll
            for (int t = 0; t < 4; t++) {
                half8 hb, lb;
                if constexpr (USE_WS) { hb = bh[t]; lb = bl[t]; }
                else                  { split_a(bf0[t], bf1[t], hb, lb); }
                accm[m][t] = __builtin_amdgcn_mfma_f32_16x16x32_f16(ah, hb, accm[m][t], 0, 0, 0);
                accl[m][t] = __builtin_amdgcn_mfma_f32_16x16x32_f16(ah, lb, accl[m][t], 0, 0, 0);
                accl[m][t] = __builtin_amdgcn_mfma_f32_16x16x32_f16(al, hb, accl[m][t], 0, 0, 0);
            }
        }
    }

    __syncthreads();      // single sync: all waves done with A-ring; alias slabs
    {   // wave ks writes its 32x64 K-partial into slab ks (8 KB, = its ring region)
        float* slab = (float*)(aring + ks * WAVE_B);
        const float inv = 1.0f / 2048.0f;
#pragma unroll
        for (int m = 0; m < 2; m++)
#pragma unroll
            for (int t = 0; t < 4; t++)
#pragma unroll
                for (int r = 0; r < 4; r++)   // C/D: row=quad*4+r, col=lane&15 [m89]
                    slab[(m * 16 + quad * 4 + r) * 64 + t * 16 + col] =
                        accm[m][t][r] + accl[m][t][r] * inv;
    }
    __syncthreads();
    {   // 512 threads: sum 8 slabs + bias -> fin[32][65]
        const int tk = tid >> 4;          // 0..31
        const int e0 = (tid & 15) * 4;    // 0..60
        floatx4 s = {0, 0, 0, 0};
#pragma unroll
        for (int p = 0; p < KSPL; p++)
            s += *(const floatx4*)((const float*)(aring + p * WAVE_B) + tk * 64 + e0);
#pragma unroll
        for (int j = 0; j < 4; j++)
            fin[tk * 65 + e0 + j] = s[j] + bsh[e0 + j];
    }
    __syncthreads();

    if (tid < TPB) {
        const int tk = tid;
        float v0 = -INFINITY, v1 = -INFINITY;
        int   i0 = 0, i1 = 0;
        for (int e = 0; e < NEXP; e++) {
            const float v = fin[tk * 65 + e];
            if (v > v0)      { v1 = v0; i1 = i0; v0 = v; i0 = e; }
            else if (v > v1) { v1 = v; i1 = e; }
        }
        const float e1 = expf(v1 - v0);   // v1 <= v0: stable
        const float sden = 1.f + e1;
        const int   g  = tok0 + tk;
        out[2 * g + 0] = 1.f / sden;
        out[2 * g + 1] = e1 / sden;
        out[2 * NTOK + 2 * g + 0] = (float)i0;
        out[2 * NTOK + 2 * g + 1] = (float)i1;
    }
}

extern "C" void kernel_launch(void* const* d_in, const int* in_sizes, int n_in,
                              void* d_out, int out_size, void* d_ws, size_t ws_size,
                              hipStream_t stream) {
    const float* x    = (const float*)d_in[0];
    const float* W    = (const float*)d_in[1];
    const float* bias = (const float*)d_in[2];
    float*       out  = (float*)d_out;
    _Float16*    wsw  = (_Float16*)d_ws;

    if (ws_size >= (size_t)WSW_BYTES) {
        hipLaunchKernelGGL(wprep_kernel, dim3(64), dim3(256), 0, stream, W, wsw);
        hipLaunchKernelGGL((gating_kernel<true>), dim3(NBLK), dim3(512), 0, stream,
                           x, W, wsw, bias, out);
    } else {
        hipLaunchKernelGGL((gating_kernel<false>), dim3(NBLK), dim3(512), 0, stream,
                           x, W, nullptr, bias, out);
    }
}